// Round 17
// baseline (301.451 us; speedup 1.0000x reference)
//
#include <hip/hip_runtime.h>
#include <hip/hip_bf16.h>

typedef __attribute__((ext_vector_type(8)))  short short8;
typedef __attribute__((ext_vector_type(4)))  float floatx4;
typedef __attribute__((ext_vector_type(16))) float floatx16;

#define N_   64
#define CIN  64
#define T_   128
#define V_   25
#define CO   128
#define MCNT 204800.0f

// ws byte offsets
#define OFF_WCF  0            // ushort[24576]  Wc A-frags (32x32): [ct4][ks12][lane64][8]
#define OFF_WDF  98304        // ushort[8192]   Wd A-frags (32x32): [ct4][ks4][lane64][8]
#define OFF_AF   131072       // ushort[3072]   adjacency B-frags (16x16) [k3][nt2][lane64][8]
#define OFF_CBD  137216       // uint[128][32]  packed (bf16(bc2), bf16(bd))
#define OFF_P1   153600       // float[2048][512] per-slot stat partials
#define OFF_SUM  4347904      // float[512]
#define OFF_STAT 4349952      // float[3][128]  s1, s2, h1+h2

__device__ __forceinline__ ushort f2bf(float f) {
    uint u = __float_as_uint(f);
    return (ushort)((u + 0x7FFFu + ((u >> 16) & 1u)) >> 16);  // RNE
}
__device__ __forceinline__ uint pack2(float a, float b) {
    return (uint)f2bf(a) | ((uint)f2bf(b) << 16);
}
// hot-path packed convert: single v_cvt_pk_bf16_f32 via HIP intrinsic (RNE)
__device__ __forceinline__ uint pk2(float a, float b) {
    __hip_bfloat162 h = __float22bfloat162_rn(make_float2(a, b));
    union { __hip_bfloat162 h2; uint u; } cv; cv.h2 = h;
    return cv.u;
}

// ---------------- k0: weight/adjacency fragment prep (grid-stride, 32 blocks) ----------------
__global__ void k0_prep(const float* __restrict__ A, const float* __restrict__ Wc,
                        const float* __restrict__ bc, const float* __restrict__ Wd,
                        const float* __restrict__ bd, void* __restrict__ wsv) {
    char* wsb = (char*)wsv;
    ushort* WCF = (ushort*)(wsb + OFF_WCF);
    ushort* WDF = (ushort*)(wsb + OFF_WDF);
    ushort* AFp = (ushort*)(wsb + OFF_AF);
    uint*   CBD = (uint*)(wsb + OFF_CBD);
    int tid = blockIdx.x * 256 + threadIdx.x;
    int stride = gridDim.x * 256;
    for (int e = tid; e < 24576; e += stride) {
        int fe = e >> 3, el = e & 7;
        int l = fe & 63, q = fe >> 6;
        int ct = q / 12, ks = q % 12;
        int j = ks*16 + ((l >> 5) << 3) + el;
        int c = ct*32 + (l & 31);
        int k = j >> 6, ci = j & 63;
        WCF[e] = f2bf(Wc[(k * CO + c) * CIN + ci]);
    }
    for (int e = tid; e < 8192; e += stride) {
        int fe = e >> 3, el = e & 7;
        int l = fe & 63, q = fe >> 6;
        int ct = q >> 2, ks = q & 3;
        int ci = ks*16 + ((l >> 5) << 3) + el;
        int c = ct*32 + (l & 31);
        WDF[e] = f2bf(Wd[c * CIN + ci]);
    }
    for (int e = tid; e < 3072; e += stride) {
        int fe = e >> 3, el = e & 7;
        int l = fe & 63, q = fe >> 6;
        int k = q >> 1, nt = q & 1;
        int w = nt*16 + (l & 15);
        int v = (l >> 4)*8 + el;
        AFp[e] = (v < V_ && w < V_) ? f2bf(A[(k*V_ + v)*V_ + w]) : (ushort)0;
    }
    for (int e = tid; e < 4096; e += stride) {
        int c = e >> 5, w = e & 31;
        float s = 0.f;
        if (w < V_) {
            for (int k = 0; k < 3; ++k) {
                float cs = 0.f;
                for (int v = 0; v < V_; ++v) cs += A[(k*V_ + v)*V_ + w];
                s += bc[k*CO + c] * cs;
            }
        }
        CBD[e] = pack2(s, bd[c]);
    }
}

// ---------------- k1: 32x32-MFMA forward, 4 slots/block, register-staged prefetch ----------------
// grid 512 (all co-resident at 2 blocks/CU); block 512 = 8 waves
// LDS 67.6 KB: XR[0,16K) | BB0[16K,32K) | BB1[32K,48K) | extra[48K,67.6K); OST=[16K,67.6K)
__global__ __launch_bounds__(512, 4) void k1_main(
        const float* __restrict__ x, void* __restrict__ wsv, uint* __restrict__ outu) {
    char* wsb = (char*)wsv;
    const ushort* WCF = (const ushort*)(wsb + OFF_WCF);
    const ushort* WDF = (const ushort*)(wsb + OFF_WDF);
    const ushort* AF  = (const ushort*)(wsb + OFF_AF);
    const uint*   CBD = (const uint*)(wsb + OFF_CBD);
    float* P1 = (float*)(wsb + OFF_P1);

    __shared__ uint SM[16896];           // 67584 B
    ushort* XR   = (ushort*)SM;
    short8* XR8  = (short8*)SM;
    uint*   XRu  = SM;
    uint*   BBu0 = SM + 4096;
    uint*   BBu1 = SM + 8192;
    short8* BB8_0 = (short8*)BBu0;
    short8* BB8_1 = (short8*)BBu1;
    uint*   OST  = SM + 4096;            // 12800 uints, excludes XR

    const int tid = threadIdx.x;
    const int l = tid & 63, wv = tid >> 6;
    const int blk = blockIdx.x;
    const int nb = blk >> 3, tg = blk & 7;
    const long xbase = (long)nb * (CIN * T_ * V_);
    const int ct = wv >> 1, nh = wv & 1;
    const int h = l >> 5, w32 = l & 31;
    const int t_a = wv & 3, nt_a = wv >> 2;
    const int g = l >> 4;

    float sf0[8], sf1[8];

    // ---- prologue: load + write slot 0 ----
    #pragma unroll
    for (int i = 0; i < 8; ++i) {
        int p = tid + i * 512;
        int ci = p >> 6, rem = p & 63, t = rem >> 4, vp = rem & 15, v = vp * 2;
        sf0[i] = 0.f; sf1[i] = 0.f;
        if (v < V_)     sf0[i] = x[xbase + ci*(T_*V_) + (tg*16 + t)*V_ + v];
        if (v + 1 < V_) sf1[i] = x[xbase + ci*(T_*V_) + (tg*16 + t)*V_ + v + 1];
    }
    #pragma unroll
    for (int i = 0; i < 8; ++i) {
        int p = tid + i * 512;
        int ci = p >> 6, rem = p & 63, t = rem >> 4, vp = rem & 15, v = vp * 2;
        int idx = (ci*4 + t)*16 + 4*((v >> 3) ^ (ci & 3)) + ((v & 7) >> 1);
        XRu[idx] = pk2(sf0[i], sf1[i]);
    }

    for (int s = 0; s < 4; ++s) {
        const int tcb = tg*4 + s;
        const int tg0 = tcb * 4;
        __syncthreads();   // B1: XR[slot s] ready; prev slot's OST reads done

        // ---- issue next slot's x loads (held in regs; written after B6) ----
        if (s < 3) {
            #pragma unroll
            for (int i = 0; i < 8; ++i) {
                int p = tid + i * 512;
                int ci = p >> 6, rem = p & 63, t = rem >> 4, vp = rem & 15, v = vp * 2;
                sf0[i] = 0.f; sf1[i] = 0.f;
                if (v < V_)     sf0[i] = x[xbase + ci*(T_*V_) + (tg0 + 4 + t)*V_ + v];
                if (v + 1 < V_) sf1[i] = x[xbase + ci*(T_*V_) + (tg0 + 4 + t)*V_ + v + 1];
            }
        }

        // ---- agg A-frags (16x16) + adjacency frags ----
        short8 xf[4];
        #pragma unroll
        for (int mt = 0; mt < 4; ++mt) {
            int ci = mt*16 + (l & 15), vg = l >> 4;
            xf[mt] = XR8[(ci*4 + t_a)*4 + (vg ^ (ci & 3))];
        }
        short8 amv[3];
        #pragma unroll
        for (int k = 0; k < 3; ++k)
            amv[k] = *(const short8*)(AF + ((k*2 + nt_a)*64 + l)*8);

        floatx16 acc0, acc1;
        #pragma unroll
        for (int i = 0; i < 16; ++i) { acc0[i] = 0.f; acc1[i] = 0.f; }

        for (int k = 0; k < 3; ++k) {
            uint* bw = (k & 1) ? BBu1 : BBu0;
            const short8* br = (k & 1) ? BB8_1 : BB8_0;
            #pragma unroll
            for (int mt = 0; mt < 4; ++mt) {
                floatx4 agc = __builtin_amdgcn_mfma_f32_16x16x32_bf16(
                    xf[mt], amv[k], (floatx4){0,0,0,0}, 0, 0, 0);
                uint u0 = pk2(agc[0], agc[1]);
                uint u1 = pk2(agc[2], agc[3]);
                int l_tgt = nt_a*16 + (l & 15) + 32*(g >> 1);
                int byteoff = ((mt*4 + t_a)*64 + l_tgt)*16 + (g & 1)*8;
                uint2 tmp; tmp.x = u0; tmp.y = u1;
                *(uint2*)((char*)bw + byteoff) = tmp;
            }
            __syncthreads();   // one barrier per k (dbuf)
            #pragma unroll
            for (int ss = 0; ss < 4; ++ss) {
                short8 a = *(const short8*)(WCF + ((ct*12 + k*4 + ss)*64 + l)*8);
                acc0 = __builtin_amdgcn_mfma_f32_32x32x16_bf16(
                    a, br[(ss*4 + nh*2 + 0)*64 + l], acc0, 0, 0, 0);
                acc1 = __builtin_amdgcn_mfma_f32_32x32x16_bf16(
                    a, br[(ss*4 + nh*2 + 1)*64 + l], acc1, 0, 0, 0);
            }
        }

        // ---- hoist packed (bc2,bd) loads; latency hides under residual GEMM ----
        uint cbdv[16];
        #pragma unroll
        for (int r = 0; r < 16; ++r) {
            int c = ct*32 + (r & 3) + 4*h + 8*(r >> 2);
            cbdv[r] = CBD[c*32 + w32];
        }

        // ---- residual B-frags (32x32) from XR -> BB1 (BB1 free: last read at k=1) ----
        #pragma unroll
        for (int i = 0; i < 2; ++i) {
            int task = tid + i*512;
            int fid = task >> 6, le = task & 63;   // fid = ks*4 + nt
            int ks = fid >> 2, nt = fid & 3;
            int wq = le & 31, hh = le >> 5;
            int cib = ks*16 + hh*8;
            short8 r8;
            #pragma unroll
            for (int e = 0; e < 8; ++e) {
                int ci = cib + e;
                r8[e] = (short)XR[ci*128 + nt*32 + 8*((wq >> 3) ^ (e & 3)) + (wq & 7)];
            }
            BB8_1[fid*64 + le] = r8;
        }
        __syncthreads();   // B5

        floatx16 racc0, racc1;
        #pragma unroll
        for (int i = 0; i < 16; ++i) { racc0[i] = 0.f; racc1[i] = 0.f; }
        #pragma unroll
        for (int ss = 0; ss < 4; ++ss) {
            short8 a = *(const short8*)(WDF + ((ct*4 + ss)*64 + l)*8);
            racc0 = __builtin_amdgcn_mfma_f32_32x32x16_bf16(
                a, BB8_1[(ss*4 + nh*2 + 0)*64 + l], racc0, 0, 0, 0);
            racc1 = __builtin_amdgcn_mfma_f32_32x32x16_bf16(
                a, BB8_1[(ss*4 + nh*2 + 1)*64 + l], racc1, 0, 0, 0);
        }
        __syncthreads();   // B6 — all XR/BB reads done; OST (BB region) free; XR writable

        // ---- write next slot's staged x into XR (outside OST overlay) ----
        if (s < 3) {
            #pragma unroll
            for (int i = 0; i < 8; ++i) {
                int p = tid + i * 512;
                int ci = p >> 6, rem = p & 63, t = rem >> 4, vp = rem & 15, v = vp * 2;
                int idx = (ci*4 + t)*16 + 4*((v >> 3) ^ (ci & 3)) + ((v & 7) >> 1);
                XRu[idx] = pk2(sf0[i], sf1[i]);
            }
        }

        // ---- pack (y2+bc2, res+bd) into OST ----
        if (w32 < V_) {
            #pragma unroll
            for (int r = 0; r < 16; ++r) {
                int c = ct*32 + (r & 3) + 4*h + 8*(r >> 2);
                float b0 = __uint_as_float(cbdv[r] << 16);
                float d0 = __uint_as_float(cbdv[r] & 0xFFFF0000u);
                OST[c*100 + (nh*2 + 0)*25 + w32] = pk2(acc0[r] + b0, racc0[r] + d0);
                OST[c*100 + (nh*2 + 1)*25 + w32] = pk2(acc1[r] + b0, racc1[r] + d0);
            }
        }
        __syncthreads();   // B7

        // ---- coalesced bulk store: 400B contiguous run per channel ----
        const long ob = (long)nb * 409600 + (long)tg0 * 25;
        for (int task = tid; task < 3200; task += 512) {
            int c = (task * 1311) >> 15;        // task/25, exact on [0,3200)
            int q = task - c * 25;
            uint4 v4 = *(const uint4*)(OST + c*100 + q*4);
            *(uint4*)(outu + ob + (long)c*3200 + q*4) = v4;
        }

        // ---- stats from OST (bf16-consistent): thread = (c, quarter) ----
        {
            int cS = tid >> 2, q4 = tid & 3;
            int s0 = (q4 == 0) ? 0 : 4 + q4*24;     // 0,28,52,76
            int n4 = (q4 == 0) ? 7 : 6;
            const uint4* op = (const uint4*)(OST + cS*100 + s0);
            float ys = 0.f, yss = 0.f, rs = 0.f, rss = 0.f;
            #pragma unroll
            for (int j = 0; j < 7; ++j) {
                if (j < n4) {
                    uint4 u = op[j];
                    #pragma unroll
                    for (int e = 0; e < 4; ++e) {
                        uint uu = (e == 0) ? u.x : (e == 1) ? u.y : (e == 2) ? u.z : u.w;
                        float yv = __uint_as_float(uu << 16);
                        float rv = __uint_as_float(uu & 0xFFFF0000u);
                        ys += yv; yss += yv*yv; rs += rv; rss += rv*rv;
                    }
                }
            }
            ys  += __shfl_xor(ys, 1);  ys  += __shfl_xor(ys, 2);
            yss += __shfl_xor(yss, 1); yss += __shfl_xor(yss, 2);
            rs  += __shfl_xor(rs, 1);  rs  += __shfl_xor(rs, 2);
            rss += __shfl_xor(rss, 1); rss += __shfl_xor(rss, 2);
            if (q4 == 0) {
                long row = (long)(blk*4 + s) * 512;
                P1[row + 0*128 + cS] = ys;
                P1[row + 1*128 + cS] = yss;
                P1[row + 2*128 + cS] = rs;
                P1[row + 3*128 + cS] = rss;
            }
        }
    }
}

// ---------------- k2a/k2b: deterministic stat reduction + folding ----------------
__global__ void k2a(void* __restrict__ wsv) {
    char* wsb = (char*)wsv;
    const float* P1 = (const float*)(wsb + OFF_P1);
    float* SUM = (float*)(wsb + OFF_SUM);
    __shared__ float red[256];
    int gc = blockIdx.x;                    // 512 blocks: gc = stream*128 + c
    float s = 0.f;
    for (int i = threadIdx.x; i < 2048; i += 256) s += P1[(long)i*512 + gc];
    red[threadIdx.x] = s; __syncthreads();
    for (int st = 128; st > 0; st >>= 1) {
        if (threadIdx.x < st) red[threadIdx.x] += red[threadIdx.x + st];
        __syncthreads();
    }
    if (threadIdx.x == 0) SUM[gc] = red[0];
}

__global__ void k2b(const float* __restrict__ gamma, const float* __restrict__ beta,
                    const float* __restrict__ gamma_d, const float* __restrict__ beta_d,
                    void* __restrict__ wsv) {
    char* wsb = (char*)wsv;
    const float* SUM = (const float*)(wsb + OFF_SUM);
    float* STAT = (float*)(wsb + OFF_STAT);
    int c = threadIdx.x;
    if (c < 128) {
        float my = SUM[c] / MCNT;
        float vy = fmaxf(SUM[128 + c] / MCNT - my*my, 0.f);
        float s1 = rsqrtf(vy + 1e-5f) * gamma[c];
        float h1 = beta[c] - my * s1;
        float mr = SUM[256 + c] / MCNT;     // res stats already include bd
        float vr = fmaxf(SUM[384 + c] / MCNT - mr*mr, 0.f);
        float s2 = rsqrtf(vr + 1e-5f) * gamma_d[c];
        float h2 = beta_d[c] - mr * s2;
        STAT[c] = s1; STAT[128 + c] = s2; STAT[256 + c] = h1 + h2;
    }
}

// ---------------- k3: in-place streaming map: packed(y2,res) -> relu(y2*s1+res*s2+h) ----------------
__global__ __launch_bounds__(256) void k3_map(void* __restrict__ wsv, uint* __restrict__ outu) {
    const float* STAT = (const float*)((const char*)wsv + OFF_STAT);
    __shared__ float sS[384];
    for (int i = threadIdx.x; i < 384; i += 256) sS[i] = STAT[i];
    __syncthreads();
    const int total4 = 6553600;                 // 26214400 uints / 4
    int stride = gridDim.x * blockDim.x;
    for (int j = blockIdx.x * blockDim.x + threadIdx.x; j < total4; j += stride) {
        uint4 u = ((const uint4*)outu)[j];
        int c = (j / 800) & 127;                // c = (4j / 3200) % 128
        float s1 = sS[c], s2 = sS[128 + c], h = sS[256 + c];
        float4 o;
        o.x = fmaxf(__uint_as_float(u.x << 16) * s1 + __uint_as_float(u.x & 0xFFFF0000u) * s2 + h, 0.f);
        o.y = fmaxf(__uint_as_float(u.y << 16) * s1 + __uint_as_float(u.y & 0xFFFF0000u) * s2 + h, 0.f);
        o.z = fmaxf(__uint_as_float(u.z << 16) * s1 + __uint_as_float(u.z & 0xFFFF0000u) * s2 + h, 0.f);
        o.w = fmaxf(__uint_as_float(u.w << 16) * s1 + __uint_as_float(u.w & 0xFFFF0000u) * s2 + h, 0.f);
        ((float4*)outu)[j] = o;
    }
}

extern "C" void kernel_launch(void* const* d_in, const int* in_sizes, int n_in,
                              void* d_out, int out_size, void* d_ws, size_t ws_size,
                              hipStream_t stream) {
    const float* x       = (const float*)d_in[0];
    const float* A       = (const float*)d_in[1];
    const float* Wc      = (const float*)d_in[2];
    const float* bc      = (const float*)d_in[3];
    const float* gamma   = (const float*)d_in[4];
    const float* beta    = (const float*)d_in[5];
    const float* Wd      = (const float*)d_in[6];
    const float* bd      = (const float*)d_in[7];
    const float* gamma_d = (const float*)d_in[8];
    const float* beta_d  = (const float*)d_in[9];
    uint* outu = (uint*)d_out;

    k0_prep<<<32, 256, 0, stream>>>(A, Wc, bc, Wd, bd, d_ws);
    k1_main<<<512, 512, 0, stream>>>(x, d_ws, outu);
    k2a<<<512, 256, 0, stream>>>(d_ws);
    k2b<<<1, 128, 0, stream>>>(gamma, beta, gamma_d, beta_d, d_ws);
    k3_map<<<2048, 256, 0, stream>>>(d_ws, outu);
}

// Round 18
// 107.124 us; speedup vs baseline: 2.8140x; 2.8140x over previous
//
#include <hip/hip_runtime.h>
#include <hip/hip_bf16.h>

typedef __attribute__((ext_vector_type(8)))  short short8;
typedef __attribute__((ext_vector_type(4)))  float floatx4;
typedef __attribute__((ext_vector_type(16))) float floatx16;

#define N_   64
#define CIN  64
#define T_   128
#define V_   25
#define CO   128
#define MCNT 204800.0f

// ws byte offsets
#define OFF_WCF  0            // ushort[24576]  Wc A-frags (32x32): [ct4][ks12][lane64][8]
#define OFF_WDF  98304        // ushort[8192]   Wd A-frags (32x32): [ct4][ks4][lane64][8]
#define OFF_AF   131072       // ushort[3072]   adjacency B-frags (16x16) [k3][nt2][lane64][8]
#define OFF_CBD  137216       // uint[128][32]  packed (bf16(bc2), bf16(bd))
#define OFF_P1   153600       // float[2048][512] per-block stat partials (blk-major)
#define OFF_SUM  4347904      // float[512]
#define OFF_STAT 4349952      // float[3][128]  s1, s2, h1+h2

__device__ __forceinline__ ushort f2bf(float f) {
    uint u = __float_as_uint(f);
    return (ushort)((u + 0x7FFFu + ((u >> 16) & 1u)) >> 16);  // RNE
}
__device__ __forceinline__ uint pack2(float a, float b) {
    return (uint)f2bf(a) | ((uint)f2bf(b) << 16);
}
// hot-path packed convert: single v_cvt_pk_bf16_f32 via HIP intrinsic (RNE)
__device__ __forceinline__ uint pk2(float a, float b) {
    __hip_bfloat162 h = __float22bfloat162_rn(make_float2(a, b));
    union { __hip_bfloat162 h2; uint u; } cv; cv.h2 = h;
    return cv.u;
}

// ---------------- k0: weight/adjacency fragment prep (grid-stride, 32 blocks) ----------------
__global__ void k0_prep(const float* __restrict__ A, const float* __restrict__ Wc,
                        const float* __restrict__ bc, const float* __restrict__ Wd,
                        const float* __restrict__ bd, void* __restrict__ wsv) {
    char* wsb = (char*)wsv;
    ushort* WCF = (ushort*)(wsb + OFF_WCF);
    ushort* WDF = (ushort*)(wsb + OFF_WDF);
    ushort* AFp = (ushort*)(wsb + OFF_AF);
    uint*   CBD = (uint*)(wsb + OFF_CBD);
    int tid = blockIdx.x * 256 + threadIdx.x;
    int stride = gridDim.x * 256;
    for (int e = tid; e < 24576; e += stride) {
        int fe = e >> 3, el = e & 7;
        int l = fe & 63, q = fe >> 6;
        int ct = q / 12, ks = q % 12;
        int j = ks*16 + ((l >> 5) << 3) + el;
        int c = ct*32 + (l & 31);
        int k = j >> 6, ci = j & 63;
        WCF[e] = f2bf(Wc[(k * CO + c) * CIN + ci]);
    }
    for (int e = tid; e < 8192; e += stride) {
        int fe = e >> 3, el = e & 7;
        int l = fe & 63, q = fe >> 6;
        int ct = q >> 2, ks = q & 3;
        int ci = ks*16 + ((l >> 5) << 3) + el;
        int c = ct*32 + (l & 31);
        WDF[e] = f2bf(Wd[c * CIN + ci]);
    }
    for (int e = tid; e < 3072; e += stride) {
        int fe = e >> 3, el = e & 7;
        int l = fe & 63, q = fe >> 6;
        int k = q >> 1, nt = q & 1;
        int w = nt*16 + (l & 15);
        int v = (l >> 4)*8 + el;
        AFp[e] = (v < V_ && w < V_) ? f2bf(A[(k*V_ + v)*V_ + w]) : (ushort)0;
    }
    for (int e = tid; e < 4096; e += stride) {
        int c = e >> 5, w = e & 31;
        float s = 0.f;
        if (w < V_) {
            for (int k = 0; k < 3; ++k) {
                float cs = 0.f;
                for (int v = 0; v < V_; ++v) cs += A[(k*V_ + v)*V_ + w];
                s += bc[k*CO + c] * cs;
            }
        }
        CBD[e] = pack2(s, bd[c]);
    }
}

// ---------------- k1: 32x32-MFMA forward; packed (y2,res) store; stats from OST ----------------
// grid 2048; block 512 = 8 waves: ct = wv>>1 (c-tile of 32), nh = wv&1 (n-tile pair)
// LDS padded to 56 KB -> 2 blocks/CU (R12: 3 blocks/CU thrashes L3 on the out-writes)
__global__ __launch_bounds__(512, 4) void k1_main(
        const float* __restrict__ x, void* __restrict__ wsv, uint* __restrict__ outu) {
    char* wsb = (char*)wsv;
    const ushort* WCF = (const ushort*)(wsb + OFF_WCF);
    const ushort* WDF = (const ushort*)(wsb + OFF_WDF);
    const ushort* AF  = (const ushort*)(wsb + OFF_AF);
    const uint*   CBD = (const uint*)(wsb + OFF_CBD);
    float* P1 = (float*)(wsb + OFF_P1);

    // 57344 B: XR[0,16K) | BB0[16K,32K) | BB1[32K,48K) | pad; OST overlays [0,51.2K)
    __shared__ uint SM[14336];
    ushort* XR   = (ushort*)SM;
    short8* XR8  = (short8*)SM;
    uint*   XRu  = SM;
    uint*   BBu0 = SM + 4096;
    uint*   BBu1 = SM + 8192;
    short8* BB8_0 = (short8*)BBu0;
    short8* BB8_1 = (short8*)BBu1;
    uint*   OST  = SM;

    const int tid = threadIdx.x;
    const int l = tid & 63, wv = tid >> 6;
    const int blk = blockIdx.x;
    const int nb = blk >> 5;
    const int r_ = blk & 31;
    const int tcb = (r_ & 7)*4 + (r_ >> 3);
    const long xbase = (long)nb * (CIN * T_ * V_);
    const int tg0 = tcb * 4;
    const int ct = wv >> 1, nh = wv & 1;
    const int h = l >> 5, w32 = l & 31;
    const int t_a = wv & 3, nt_a = wv >> 2;

    // ---- stage x -> XR ([ci][t][v32], 16B-slot XOR swizzle) — single staging ----
    #pragma unroll
    for (int i = 0; i < 8; ++i) {
        int p = tid + i * 512;
        int ci = p >> 6, rem = p & 63, t = rem >> 4, vp = rem & 15, v = vp * 2;
        float f0 = 0.f, f1 = 0.f;
        if (v < V_)     f0 = x[xbase + ci*(T_*V_) + (tg0 + t)*V_ + v];
        if (v + 1 < V_) f1 = x[xbase + ci*(T_*V_) + (tg0 + t)*V_ + v + 1];
        int idx = (ci*4 + t)*16 + 4*((v >> 3) ^ (ci & 3)) + ((v & 7) >> 1);
        XRu[idx] = pk2(f0, f1);
    }
    __syncthreads();   // B1

    // ---- agg A-frags (16x16) + adjacency frags ----
    short8 xf[4];
    #pragma unroll
    for (int mt = 0; mt < 4; ++mt) {
        int ci = mt*16 + (l & 15), vg = l >> 4;
        xf[mt] = XR8[(ci*4 + t_a)*4 + (vg ^ (ci & 3))];
    }
    short8 amv[3];
    #pragma unroll
    for (int k = 0; k < 3; ++k)
        amv[k] = *(const short8*)(AF + ((k*2 + nt_a)*64 + l)*8);

    floatx16 acc0, acc1;
    #pragma unroll
    for (int i = 0; i < 16; ++i) { acc0[i] = 0.f; acc1[i] = 0.f; }

    const int g = l >> 4;
    for (int k = 0; k < 3; ++k) {
        uint* bw = (k & 1) ? BBu1 : BBu0;
        const short8* br = (k & 1) ? BB8_1 : BB8_0;
        // agg (16x16) -> repack into 32x32 B-frag layout; one uint2 per mt
        #pragma unroll
        for (int mt = 0; mt < 4; ++mt) {
            floatx4 agc = __builtin_amdgcn_mfma_f32_16x16x32_bf16(
                xf[mt], amv[k], (floatx4){0,0,0,0}, 0, 0, 0);
            uint u0 = pk2(agc[0], agc[1]);
            uint u1 = pk2(agc[2], agc[3]);
            int l_tgt = nt_a*16 + (l & 15) + 32*(g >> 1);
            int byteoff = ((mt*4 + t_a)*64 + l_tgt)*16 + (g & 1)*8;
            uint2 tmp; tmp.x = u0; tmp.y = u1;
            *(uint2*)((char*)bw + byteoff) = tmp;
        }
        __syncthreads();   // one barrier per k (dbuf)
        // main GEMM: 32x32x16, 2 tiles (nt = nh*2, nh*2+1)
        #pragma unroll
        for (int s = 0; s < 4; ++s) {
            short8 a = *(const short8*)(WCF + ((ct*12 + k*4 + s)*64 + l)*8);
            acc0 = __builtin_amdgcn_mfma_f32_32x32x16_bf16(
                a, br[(s*4 + nh*2 + 0)*64 + l], acc0, 0, 0, 0);
            acc1 = __builtin_amdgcn_mfma_f32_32x32x16_bf16(
                a, br[(s*4 + nh*2 + 1)*64 + l], acc1, 0, 0, 0);
        }
    }

    // ---- hoist packed (bc2,bd) loads; latency hides under residual phase ----
    uint cbdv[16];
    #pragma unroll
    for (int r = 0; r < 16; ++r) {
        int c = ct*32 + (r & 3) + 4*h + 8*(r >> 2);
        cbdv[r] = CBD[c*32 + w32];
    }

    // ---- residual B-frags (32x32) straight from XR (16 u16 reads; R12-verified) ----
    // k=2 GEMM read BB8_0, writes here go to BB8_1: race-free without barrier
    #pragma unroll
    for (int i = 0; i < 2; ++i) {
        int task = tid + i*512;
        int fid = task >> 6, le = task & 63;   // fid = ks*4 + nt
        int ks = fid >> 2, nt = fid & 3;
        int wq = le & 31, hh = le >> 5;
        int cib = ks*16 + hh*8;
        short8 r8;
        #pragma unroll
        for (int e = 0; e < 8; ++e) {
            int ci = cib + e;
            r8[e] = (short)XR[ci*128 + nt*32 + 8*((wq >> 3) ^ (e & 3)) + (wq & 7)];
        }
        BB8_1[fid*64 + le] = r8;
    }
    __syncthreads();   // B5

    floatx16 racc0, racc1;
    #pragma unroll
    for (int i = 0; i < 16; ++i) { racc0[i] = 0.f; racc1[i] = 0.f; }
    #pragma unroll
    for (int s = 0; s < 4; ++s) {
        short8 a = *(const short8*)(WDF + ((ct*4 + s)*64 + l)*8);
        racc0 = __builtin_amdgcn_mfma_f32_32x32x16_bf16(
            a, BB8_1[(s*4 + nh*2 + 0)*64 + l], racc0, 0, 0, 0);
        racc1 = __builtin_amdgcn_mfma_f32_32x32x16_bf16(
            a, BB8_1[(s*4 + nh*2 + 1)*64 + l], racc1, 0, 0, 0);
    }
    __syncthreads();   // B6 — all XR/BB reads done; OST may overlay

    // ---- pack (y2+bc2, res+bd) into OST ----
    if (w32 < V_) {
        #pragma unroll
        for (int r = 0; r < 16; ++r) {
            int c = ct*32 + (r & 3) + 4*h + 8*(r >> 2);
            float b0 = __uint_as_float(cbdv[r] << 16);
            float d0 = __uint_as_float(cbdv[r] & 0xFFFF0000u);
            OST[c*100 + (nh*2 + 0)*25 + w32] = pk2(acc0[r] + b0, racc0[r] + d0);
            OST[c*100 + (nh*2 + 1)*25 + w32] = pk2(acc1[r] + b0, racc1[r] + d0);
        }
    }
    __syncthreads();   // B7

    // ---- coalesced bulk store: 400B contiguous run per channel ----
    const long ob = (long)nb * 409600 + (long)tg0 * 25;
    for (int task = tid; task < 3200; task += 512) {
        int c = (task * 1311) >> 15;        // task/25, exact on [0,3200)
        int q = task - c * 25;
        uint4 v4 = *(const uint4*)(OST + c*100 + q*4);
        *(uint4*)(outu + ob + (long)c*3200 + q*4) = v4;
    }

    // ---- stats from OST (bf16-consistent): thread = (c, quarter) ----
    {
        int cS = tid >> 2, q4 = tid & 3;
        int s0 = (q4 == 0) ? 0 : 4 + q4*24;     // 0,28,52,76
        int n4 = (q4 == 0) ? 7 : 6;
        const uint4* op = (const uint4*)(OST + cS*100 + s0);
        float ys = 0.f, yss = 0.f, rs = 0.f, rss = 0.f;
        #pragma unroll
        for (int j = 0; j < 7; ++j) {
            if (j < n4) {
                uint4 u = op[j];
                #pragma unroll
                for (int e = 0; e < 4; ++e) {
                    uint uu = (e == 0) ? u.x : (e == 1) ? u.y : (e == 2) ? u.z : u.w;
                    float yv = __uint_as_float(uu << 16);
                    float rv = __uint_as_float(uu & 0xFFFF0000u);
                    ys += yv; yss += yv*yv; rs += rv; rss += rv*rv;
                }
            }
        }
        ys  += __shfl_xor(ys, 1);  ys  += __shfl_xor(ys, 2);
        yss += __shfl_xor(yss, 1); yss += __shfl_xor(yss, 2);
        rs  += __shfl_xor(rs, 1);  rs  += __shfl_xor(rs, 2);
        rss += __shfl_xor(rss, 1); rss += __shfl_xor(rss, 2);
        if (q4 == 0) {
            P1[(long)blk*512 + 0*128 + cS] = ys;
            P1[(long)blk*512 + 1*128 + cS] = yss;
            P1[(long)blk*512 + 2*128 + cS] = rs;
            P1[(long)blk*512 + 3*128 + cS] = rss;
        }
    }
}

// ---------------- k2a/k2b: deterministic stat reduction + folding ----------------
__global__ void k2a(void* __restrict__ wsv) {
    char* wsb = (char*)wsv;
    const float* P1 = (const float*)(wsb + OFF_P1);
    float* SUM = (float*)(wsb + OFF_SUM);
    __shared__ float red[256];
    int gc = blockIdx.x;                    // 512 blocks: gc = stream*128 + c
    float s = 0.f;
    for (int i = threadIdx.x; i < 2048; i += 256) s += P1[(long)i*512 + gc];
    red[threadIdx.x] = s; __syncthreads();
    for (int st = 128; st > 0; st >>= 1) {
        if (threadIdx.x < st) red[threadIdx.x] += red[threadIdx.x + st];
        __syncthreads();
    }
    if (threadIdx.x == 0) SUM[gc] = red[0];
}

__global__ void k2b(const float* __restrict__ gamma, const float* __restrict__ beta,
                    const float* __restrict__ gamma_d, const float* __restrict__ beta_d,
                    void* __restrict__ wsv) {
    char* wsb = (char*)wsv;
    const float* SUM = (const float*)(wsb + OFF_SUM);
    float* STAT = (float*)(wsb + OFF_STAT);
    int c = threadIdx.x;
    if (c < 128) {
        float my = SUM[c] / MCNT;
        float vy = fmaxf(SUM[128 + c] / MCNT - my*my, 0.f);
        float s1 = rsqrtf(vy + 1e-5f) * gamma[c];
        float h1 = beta[c] - my * s1;
        float mr = SUM[256 + c] / MCNT;     // res stats already include bd
        float vr = fmaxf(SUM[384 + c] / MCNT - mr*mr, 0.f);
        float s2 = rsqrtf(vr + 1e-5f) * gamma_d[c];
        float h2 = beta_d[c] - mr * s2;
        STAT[c] = s1; STAT[128 + c] = s2; STAT[256 + c] = h1 + h2;
    }
}

// ---------------- k3: in-place streaming map: packed(y2,res) -> relu(y2*s1+res*s2+h) ----------------
__global__ __launch_bounds__(256) void k3_map(void* __restrict__ wsv, uint* __restrict__ outu) {
    const float* STAT = (const float*)((const char*)wsv + OFF_STAT);
    __shared__ float sS[384];
    for (int i = threadIdx.x; i < 384; i += 256) sS[i] = STAT[i];
    __syncthreads();
    const int total4 = 6553600;                 // 26214400 uints / 4
    int stride = gridDim.x * blockDim.x;
    for (int j = blockIdx.x * blockDim.x + threadIdx.x; j < total4; j += stride) {
        uint4 u = ((const uint4*)outu)[j];
        int c = (j / 800) & 127;                // c = (4j / 3200) % 128
        float s1 = sS[c], s2 = sS[128 + c], h = sS[256 + c];
        float4 o;
        o.x = fmaxf(__uint_as_float(u.x << 16) * s1 + __uint_as_float(u.x & 0xFFFF0000u) * s2 + h, 0.f);
        o.y = fmaxf(__uint_as_float(u.y << 16) * s1 + __uint_as_float(u.y & 0xFFFF0000u) * s2 + h, 0.f);
        o.z = fmaxf(__uint_as_float(u.z << 16) * s1 + __uint_as_float(u.z & 0xFFFF0000u) * s2 + h, 0.f);
        o.w = fmaxf(__uint_as_float(u.w << 16) * s1 + __uint_as_float(u.w & 0xFFFF0000u) * s2 + h, 0.f);
        ((float4*)outu)[j] = o;
    }
}

extern "C" void kernel_launch(void* const* d_in, const int* in_sizes, int n_in,
                              void* d_out, int out_size, void* d_ws, size_t ws_size,
                              hipStream_t stream) {
    const float* x       = (const float*)d_in[0];
    const float* A       = (const float*)d_in[1];
    const float* Wc      = (const float*)d_in[2];
    const float* bc      = (const float*)d_in[3];
    const float* gamma   = (const float*)d_in[4];
    const float* beta    = (const float*)d_in[5];
    const float* Wd      = (const float*)d_in[6];
    const float* bd      = (const float*)d_in[7];
    const float* gamma_d = (const float*)d_in[8];
    const float* beta_d  = (const float*)d_in[9];
    uint* outu = (uint*)d_out;

    k0_prep<<<32, 256, 0, stream>>>(A, Wc, bc, Wd, bd, d_ws);
    k1_main<<<2048, 512, 0, stream>>>(x, d_ws, outu);
    k2a<<<512, 256, 0, stream>>>(d_ws);
    k2b<<<1, 128, 0, stream>>>(gamma, beta, gamma_d, beta_d, d_ws);
    k3_map<<<2048, 256, 0, stream>>>(d_ws, outu);
}